// Round 3
// baseline (742.787 us; speedup 1.0000x reference)
//
#include <hip/hip_runtime.h>
#include <hip/hip_bf16.h>
#include <math.h>

#define BT   16384
#define HIDS 256
#define NHS  8
#define NVS  20

typedef __attribute__((ext_vector_type(8))) short short8;
typedef __attribute__((ext_vector_type(4))) float floatx4;

__device__ __forceinline__ float bf2f(unsigned int u) {
    union { unsigned int u; float f; } cv; cv.u = u << 16; return cv.f;
}
__device__ __forceinline__ unsigned short f2bf(float f) {
    union { __hip_bfloat16 h; unsigned short u; } cv; cv.h = __float2bfloat16(f); return cv.u;
}
__device__ __forceinline__ unsigned int pk2(float a, float b) {
    return (unsigned int)f2bf(a) | ((unsigned int)f2bf(b) << 16);
}
__device__ __forceinline__ void gload16(const void* g, void* l) {
    __builtin_amdgcn_global_load_lds(
        (const __attribute__((address_space(1))) unsigned int*)g,
        (__attribute__((address_space(3))) unsigned int*)l, 16, 0, 0);
}

// ---------- prep: fold query into key proj -> qkbT [16][256] bf16, qb[8] ----------
__global__ __launch_bounds__(256) void k_fold(
        const float* __restrict__ cls, const float* __restrict__ wq,
        const float* __restrict__ bq, const float* __restrict__ wk,
        const float* __restrict__ bk, unsigned short* __restrict__ qkbT,
        float* __restrict__ qb) {
    __shared__ float s_q[HIDS];
    int tid = threadIdx.x;
    float acc = bq[tid];
    for (int c = 0; c < HIDS; ++c) acc += cls[c] * wq[c * HIDS + tid];
    s_q[tid] = acc;
    __syncthreads();
    int c = tid;
    #pragma unroll
    for (int h = 0; h < NHS; ++h) {
        float a = 0.f;
        #pragma unroll
        for (int d = 0; d < 32; ++d) a += wk[c * HIDS + h * 32 + d] * s_q[h * 32 + d];
        qkbT[h * HIDS + c] = f2bf(a);
    }
    #pragma unroll
    for (int h = NHS; h < 16; ++h) qkbT[h * HIDS + c] = 0;
    if (tid < NHS) {
        float a = 0.f;
        #pragma unroll
        for (int d = 0; d < 32; ++d) a += bk[tid * 32 + d] * s_q[tid * 32 + d];
        qb[tid] = a;
    }
}

// ---------- prep: bvo = bv@wo + bo ----------
__global__ __launch_bounds__(256) void k_bvo(
        const float* __restrict__ bv, const float* __restrict__ wo,
        const float* __restrict__ bo, float* __restrict__ bvo) {
    int j = threadIdx.x;
    float a = bo[j];
    for (int i = 0; i < HIDS; ++i) a += bv[i] * wo[i * HIDS + j];
    bvo[j] = a;
}

// ---------- prep: wvo_t[j][h*256+c] = sum_d wv[c][h*32+d]*wo[h*32+d][j] (bf16) ----
// coalesced loads + coalesced stores; grid 32 = (h, j-quarter)
__global__ __launch_bounds__(256) void k_wvo(
        const float* __restrict__ wv, const float* __restrict__ wo,
        unsigned short* __restrict__ wvo_t) {
    int h = blockIdx.x >> 2;
    int j0 = (blockIdx.x & 3) * 64;
    int tid = threadIdx.x;  // c
    __shared__ float s_wo[32][64];
    #pragma unroll
    for (int i = 0; i < 8; ++i) {
        int idx = i * 256 + tid;
        int d = idx >> 6, jj = idx & 63;
        s_wo[d][jj] = wo[(h * 32 + d) * HIDS + j0 + jj];
    }
    float av[32];
    #pragma unroll
    for (int d4 = 0; d4 < 8; ++d4) {
        float4 f = *(const float4*)(wv + (size_t)tid * HIDS + h * 32 + d4 * 4);
        av[d4 * 4] = f.x; av[d4 * 4 + 1] = f.y;
        av[d4 * 4 + 2] = f.z; av[d4 * 4 + 3] = f.w;
    }
    __syncthreads();
    #pragma unroll 4
    for (int jj = 0; jj < 64; ++jj) {
        float a = 0.f;
        #pragma unroll
        for (int d = 0; d < 32; ++d) a += av[d] * s_wo[d][jj];
        wvo_t[(size_t)(j0 + jj) * 2048 + h * 256 + tid] = f2bf(a);
    }
}

// ---------- prep: transpose f32 [R][C] -> bf16 [C][R] ----------
__global__ __launch_bounds__(256) void k_transp(const float* __restrict__ in,
        unsigned short* __restrict__ out, int R, int C) {
    __shared__ float s[32][36];
    int tid = threadIdx.x;
    int ct = blockIdx.x * 32, rt = blockIdx.y * 32;
    int r = tid >> 3, c4 = (tid & 7) * 4;
    float4 f = *(const float4*)&in[(size_t)(rt + r) * C + ct + c4];
    s[r][c4] = f.x; s[r][c4 + 1] = f.y; s[r][c4 + 2] = f.z; s[r][c4 + 3] = f.w;
    __syncthreads();
    int ro = tid >> 3, k4 = (tid & 7) * 4;
    ushort4 o;
    o.x = f2bf(s[k4][ro]);     o.y = f2bf(s[k4 + 1][ro]);
    o.z = f2bf(s[k4 + 2][ro]); o.w = f2bf(s[k4 + 3][ro]);
    *(ushort4*)&out[(size_t)(ct + ro) * R + rt + k4] = o;
}

// ---------- attention: 4 tokens/block, MFMA scores, VALU mix -> xmix bf16 ----------
__global__ __launch_bounds__(256) void k_attn(
        const float* __restrict__ x, const unsigned short* __restrict__ qkbT,
        const float* __restrict__ qb, unsigned short* __restrict__ xmix) {
    __shared__ __align__(16) unsigned short sX[92 * 256];
    __shared__ float s_at[4][NVS][NHS];
    int tid = threadIdx.x;
    int wave = tid >> 6, lane = tid & 63;
    int m = lane & 15, g = lane >> 4;
    size_t t0 = (size_t)blockIdx.x * 4;

    short8 qf[8];
    #pragma unroll
    for (int kk = 0; kk < 8; ++kk)
        qf[kk] = *(const short8*)&qkbT[m * HIDS + kk * 32 + g * 8];

    const float* xg = x + t0 * (NVS * HIDS);
    #pragma unroll
    for (int i = 0; i < 10; ++i) {
        int s = i * 256 + tid;
        int row = s >> 5, cc = s & 31;
        float4 f0 = *(const float4*)(xg + s * 8);
        float4 f1 = *(const float4*)(xg + s * 8 + 4);
        uint4 pk;
        pk.x = pk2(f0.x, f0.y); pk.y = pk2(f0.z, f0.w);
        pk.z = pk2(f1.x, f1.y); pk.w = pk2(f1.z, f1.w);
        int c = cc ^ (row & 7);
        *(uint4*)&sX[row * 256 + c * 8] = pk;
    }
    __syncthreads();

    int rbase = wave * NVS;
    floatx4 sc0 = {0.f, 0.f, 0.f, 0.f}, sc1 = {0.f, 0.f, 0.f, 0.f};
    #pragma unroll
    for (int kk = 0; kk < 8; ++kk) {
        int r0 = rbase + m;
        int c0 = (kk * 4 + g) ^ (r0 & 7);
        short8 a0 = *(const short8*)&sX[r0 * 256 + c0 * 8];
        int r1 = rbase + 16 + m;
        int c1 = (kk * 4 + g) ^ (r1 & 7);
        short8 a1 = *(const short8*)&sX[r1 * 256 + c1 * 8];
        sc0 = __builtin_amdgcn_mfma_f32_16x16x32_bf16(a0, qf[kk], sc0, 0, 0, 0);
        sc1 = __builtin_amdgcn_mfma_f32_16x16x32_bf16(a1, qf[kk], sc1, 0, 0, 0);
    }
    if (m < NHS) {
        #pragma unroll
        for (int r = 0; r < 4; ++r) s_at[wave][g * 4 + r][m] = sc0[r];
        if (g == 0) {
            #pragma unroll
            for (int r = 0; r < 4; ++r) s_at[wave][16 + r][m] = sc1[r];
        }
    }
    __syncthreads();

    if (lane < NHS) {
        float qbh = qb[lane];
        float sv[NVS]; float mx = -1e30f;
        #pragma unroll
        for (int v = 0; v < NVS; ++v) {
            float sc = (s_at[wave][v][lane] + qbh) * 0.17677669529663687f;
            sv[v] = sc; mx = fmaxf(mx, sc);
        }
        float sum = 0.f;
        #pragma unroll
        for (int v = 0; v < NVS; ++v) { sv[v] = expf(sv[v] - mx); sum += sv[v]; }
        float inv = 1.f / sum;
        #pragma unroll
        for (int v = 0; v < NVS; ++v) s_at[wave][v][lane] = sv[v] * inv;
    }
    __syncthreads();

    floatx4 acc[NHS];
    #pragma unroll
    for (int h = 0; h < NHS; ++h) acc[h] = (floatx4){0.f, 0.f, 0.f, 0.f};
    #pragma unroll
    for (int v = 0; v < NVS; ++v) {
        int r = rbase + v;
        int cidx = (((lane >> 1) ^ (r & 7)) << 3) + ((lane & 1) << 2);
        uint2 u = *(const uint2*)&sX[r * 256 + cidx];
        float x0 = bf2f(u.x & 0xffffu), x1 = bf2f(u.x >> 16);
        float x2 = bf2f(u.y & 0xffffu), x3 = bf2f(u.y >> 16);
        float4 w0 = *(const float4*)&s_at[wave][v][0];
        float4 w1 = *(const float4*)&s_at[wave][v][4];
        float wv8[8] = {w0.x, w0.y, w0.z, w0.w, w1.x, w1.y, w1.z, w1.w};
        #pragma unroll
        for (int h = 0; h < NHS; ++h) {
            acc[h][0] += wv8[h] * x0; acc[h][1] += wv8[h] * x1;
            acc[h][2] += wv8[h] * x2; acc[h][3] += wv8[h] * x3;
        }
    }
    unsigned short* op = xmix + (t0 + wave) * 2048;
    #pragma unroll
    for (int h = 0; h < NHS; ++h) {
        uint2 o; o.x = pk2(acc[h][0], acc[h][1]); o.y = pk2(acc[h][2], acc[h][3]);
        *(uint2*)&op[h * 256 + lane * 4] = o;
    }
}

// ---------- MFMA GEMM, BM=32 BN=256 BK=64: out = post(A @ Bt^T + bias) ----------
// LN=true requires NTOT==256 and grid.y==1 (block owns full rows).
template <int K, int NTOT, bool GELU, bool LN, bool OUTF32>
__global__ __launch_bounds__(256) void k_mg(
        const unsigned short* __restrict__ A,
        const unsigned short* __restrict__ Bt,
        const float* __restrict__ bias,
        const float* __restrict__ lng, const float* __restrict__ lnb,
        void* __restrict__ outp) {
    constexpr int BM = 32, BK = 64;
    __shared__ __align__(16) unsigned short sA[BM * BK];
    __shared__ __align__(16) unsigned short sB[256 * BK];
    __shared__ float s_sum[4][BM], s_sq[4][BM], s_ms[BM][2];
    int tid = threadIdx.x;
    int wave = tid >> 6, lane = tid & 63;
    int m = lane & 15, g = lane >> 4;
    int wn = wave * 64;
    size_t t0 = (size_t)blockIdx.x * BM;
    int n0 = blockIdx.y * 256;

    floatx4 acc[2][4];
    #pragma unroll
    for (int i = 0; i < 2; ++i)
        #pragma unroll
        for (int j = 0; j < 4; ++j) acc[i][j] = (floatx4){0.f, 0.f, 0.f, 0.f};

    for (int k0 = 0; k0 < K; k0 += BK) {
        __syncthreads();
        {
            int s = tid;
            int row = s >> 3, cc = s & 7;
            int gc = cc ^ (row & 7);
            gload16(A + (t0 + row) * K + k0 + gc * 8, (char*)sA + s * 16);
        }
        #pragma unroll
        for (int i = 0; i < 8; ++i) {
            int s = i * 256 + tid;
            int row = s >> 3, cc = s & 7;
            int gc = cc ^ (row & 7);
            gload16(Bt + (size_t)(n0 + row) * K + k0 + gc * 8, (char*)sB + s * 16);
        }
        __syncthreads();
        #pragma unroll
        for (int kk = 0; kk < 2; ++kk) {
            short8 af[2]; short8 bfr[4];
            #pragma unroll
            for (int i = 0; i < 2; ++i) {
                int row = i * 16 + m;
                int c = (kk * 4 + g) ^ (row & 7);
                af[i] = *(const short8*)&sA[row * BK + c * 8];
            }
            #pragma unroll
            for (int j = 0; j < 4; ++j) {
                int row = wn + j * 16 + m;
                int c = (kk * 4 + g) ^ (row & 7);
                bfr[j] = *(const short8*)&sB[row * BK + c * 8];
            }
            #pragma unroll
            for (int i = 0; i < 2; ++i)
                #pragma unroll
                for (int j = 0; j < 4; ++j)
                    acc[i][j] = __builtin_amdgcn_mfma_f32_16x16x32_bf16(af[i], bfr[j], acc[i][j], 0, 0, 0);
        }
    }

    float vv[2][4][4];
    #pragma unroll
    for (int j = 0; j < 4; ++j) {
        float bj = bias[n0 + wn + j * 16 + m];
        #pragma unroll
        for (int i = 0; i < 2; ++i)
            #pragma unroll
            for (int r = 0; r < 4; ++r) {
                float v = acc[i][j][r] + bj;
                if (GELU) v = 0.5f * v * (1.f + erff(v * 0.70710678118654752f));
                vv[i][j][r] = v;
            }
    }

    if (LN) {
        float ps[2][4], pq[2][4];
        #pragma unroll
        for (int i = 0; i < 2; ++i)
            #pragma unroll
            for (int r = 0; r < 4; ++r) {
                float s = 0.f, q = 0.f;
                #pragma unroll
                for (int j = 0; j < 4; ++j) { float v = vv[i][j][r]; s += v; q += v * v; }
                #pragma unroll
                for (int mk = 1; mk < 16; mk <<= 1) {
                    s += __shfl_xor(s, mk, 64);
                    q += __shfl_xor(q, mk, 64);
                }
                ps[i][r] = s; pq[i][r] = q;
            }
        if ((lane & 15) == 0) {
            #pragma unroll
            for (int i = 0; i < 2; ++i)
                #pragma unroll
                for (int r = 0; r < 4; ++r) {
                    int row = i * 16 + g * 4 + r;
                    s_sum[wave][row] = ps[i][r];
                    s_sq[wave][row] = pq[i][r];
                }
        }
        __syncthreads();
        if (tid < BM) {
            float ts = 0.f, tq = 0.f;
            #pragma unroll
            for (int w = 0; w < 4; ++w) { ts += s_sum[w][tid]; tq += s_sq[w][tid]; }
            float mean = ts * (1.f / 256.f);
            float var = tq * (1.f / 256.f) - mean * mean;
            s_ms[tid][0] = mean; s_ms[tid][1] = rsqrtf(var + 1e-5f);
        }
        __syncthreads();
        float lg[4], lb[4];
        #pragma unroll
        for (int j = 0; j < 4; ++j) {
            lg[j] = lng[wn + j * 16 + m];
            lb[j] = lnb[wn + j * 16 + m];
        }
        #pragma unroll
        for (int i = 0; i < 2; ++i)
            #pragma unroll
            for (int r = 0; r < 4; ++r) {
                int row = i * 16 + g * 4 + r;
                float mean = s_ms[row][0], rstd = s_ms[row][1];
                #pragma unroll
                for (int j = 0; j < 4; ++j)
                    vv[i][j][r] = (vv[i][j][r] - mean) * rstd * lg[j] + lb[j];
            }
    }

    #pragma unroll
    for (int i = 0; i < 2; ++i)
        #pragma unroll
        for (int r = 0; r < 4; ++r) {
            size_t grow = t0 + i * 16 + g * 4 + r;
            #pragma unroll
            for (int j = 0; j < 4; ++j) {
                float v = vv[i][j][r];
                if (OUTF32) {
                    ((float*)outp)[grow * NTOT + n0 + wn + j * 16 + m] = v;
                } else {
                    float v2 = __shfl_xor(v, 1);
                    if (!(lane & 1))
                        *(unsigned int*)((unsigned short*)outp + grow * NTOT + n0 + wn + j * 16 + m) = pk2(v, v2);
                }
            }
        }
}

// ---------- fused LN2 + selection logits + softmax + vs_output ----------
__global__ __launch_bounds__(256) void k_wsel(
        const float* __restrict__ in, const float* __restrict__ lng,
        const float* __restrict__ lnb, const float* __restrict__ ww,
        const float* __restrict__ bw, const float* __restrict__ x,
        float* __restrict__ wout, float* __restrict__ vs_out) {
    __shared__ float s_p[16][HIDS + 1];
    __shared__ float s_red[2][16][16];
    __shared__ float s_ms[16][2];
    __shared__ float s_lg[16][NVS];
    __shared__ float s_w[16][NVS];
    int tid = threadIdx.x;
    size_t t0 = (size_t)blockIdx.x * 16;
    #pragma unroll
    for (int i = 0; i < 4; ++i) {
        int idx4 = i * 256 + tid;
        float4 f = ((const float4*)(in + t0 * HIDS))[idx4];
        int flat = idx4 * 4;
        int r = flat >> 8, c = flat & 255;
        s_p[r][c] = f.x; s_p[r][c + 1] = f.y; s_p[r][c + 2] = f.z; s_p[r][c + 3] = f.w;
    }
    __syncthreads();
    int r = tid >> 4, jg = tid & 15;
    float sum = 0.f, sq = 0.f;
    #pragma unroll
    for (int i = 0; i < 16; ++i) {
        float a = s_p[r][jg * 16 + i]; sum += a; sq += a * a;
    }
    s_red[0][r][jg] = sum; s_red[1][r][jg] = sq;
    __syncthreads();
    if (jg == 0) {
        float ts = 0.f, tq = 0.f;
        #pragma unroll
        for (int i = 0; i < 16; ++i) { ts += s_red[0][r][i]; tq += s_red[1][r][i]; }
        float mean = ts * (1.f / HIDS);
        float var = tq * (1.f / HIDS) - mean * mean;
        s_ms[r][0] = mean; s_ms[r][1] = rsqrtf(var + 1e-5f);
    }
    __syncthreads();
    float mean = s_ms[r][0], rstd = s_ms[r][1];
    #pragma unroll
    for (int i = 0; i < 16; ++i) {
        int c = jg * 16 + i;
        s_p[r][c] = (s_p[r][c] - mean) * rstd * lng[c] + lnb[c];
    }
    __syncthreads();
    if (jg < 10) {
        int o = jg * 2;
        float a0 = bw[o], a1 = bw[o + 1];
        #pragma unroll 4
        for (int c = 0; c < HIDS; ++c) {
            float a = s_p[r][c];
            const float2 w = *(const float2*)(ww + c * NVS + o);
            a0 += a * w.x; a1 += a * w.y;
        }
        s_lg[r][o] = a0; s_lg[r][o + 1] = a1;
    }
    __syncthreads();
    if (tid < 16) {
        int rr = tid;
        float mx = -1e30f;
        #pragma unroll
        for (int v = 0; v < NVS; ++v) mx = fmaxf(mx, s_lg[rr][v]);
        float e[NVS]; float ssum = 0.f;
        #pragma unroll
        for (int v = 0; v < NVS; ++v) { e[v] = expf(s_lg[rr][v] - mx); ssum += e[v]; }
        float inv = 1.f / ssum;
        #pragma unroll
        for (int v = 0; v < NVS; ++v) {
            float wv_ = e[v] * inv;
            s_w[rr][v] = wv_;
            wout[(t0 + rr) * NVS + v] = wv_;
        }
    }
    __syncthreads();
    int wave = tid >> 6, l = tid & 63;
    #pragma unroll
    for (int tt = 0; tt < 4; ++tt) {
        int t = wave * 4 + tt;
        const float4* xt = (const float4*)(x + (t0 + t) * (NVS * HIDS));
        float4 acc = make_float4(0.f, 0.f, 0.f, 0.f);
        #pragma unroll
        for (int v = 0; v < NVS; ++v) {
            float w = s_w[t][v];
            float4 a = xt[v * 64 + l];
            acc.x += w * a.x; acc.y += w * a.y; acc.z += w * a.z; acc.w += w * a.w;
        }
        ((float4*)(vs_out + (t0 + t) * HIDS))[l] = acc;
    }
}

extern "C" void kernel_launch(void* const* d_in, const int* in_sizes, int n_in,
                              void* d_out, int out_size, void* d_ws, size_t ws_size,
                              hipStream_t stream) {
    const float* x     = (const float*)d_in[0];
    const float* cls   = (const float*)d_in[1];
    const float* wq    = (const float*)d_in[2];
    const float* bq    = (const float*)d_in[3];
    const float* wk    = (const float*)d_in[4];
    const float* bk    = (const float*)d_in[5];
    const float* wv    = (const float*)d_in[6];
    const float* bv    = (const float*)d_in[7];
    const float* wo    = (const float*)d_in[8];
    const float* bo    = (const float*)d_in[9];
    const float* ln1_g = (const float*)d_in[10];
    const float* ln1_b = (const float*)d_in[11];
    const float* w1    = (const float*)d_in[12];
    const float* b1    = (const float*)d_in[13];
    const float* w2    = (const float*)d_in[14];
    const float* b2    = (const float*)d_in[15];
    const float* ln2_g = (const float*)d_in[16];
    const float* ln2_b = (const float*)d_in[17];
    const float* ww    = (const float*)d_in[18];
    const float* bw    = (const float*)d_in[19];

    float* outf   = (float*)d_out;
    float* vs_out = outf;
    float* w_out  = outf + (size_t)BT * HIDS;

    char* ws = (char*)d_ws;
    unsigned short* qkbT = (unsigned short*)ws;                          // 8 KB
    float* qb   = (float*)(ws + 8192);
    float* bvo  = (float*)(ws + 8448);
    unsigned short* w1t   = (unsigned short*)(ws + 16384);               // 512 KB
    unsigned short* w2t   = (unsigned short*)(ws + 16384 + 524288);      // 512 KB
    unsigned short* wvo_t = (unsigned short*)(ws + 16384 + 1048576);     // 1 MB
    char* big = ws + 16384 + 1048576 + 1048576;
    unsigned short* bufA = (unsigned short*)big;                         // 67.1 MB (xmix then h1)
    unsigned short* hb   = (unsigned short*)(big + (size_t)BT * 2048 * 2);       // 8.4 MB (LN1 out bf16)
    float* buf1 = (float*)(big + (size_t)BT * 2048 * 2 + (size_t)BT * HIDS * 2); // 16.8 MB (GEMM3 out f32)

    // prep
    k_fold<<<1, 256, 0, stream>>>(cls, wq, bq, wk, bk, qkbT, qb);
    k_bvo<<<1, 256, 0, stream>>>(bv, wo, bo, bvo);
    k_wvo<<<32, 256, 0, stream>>>(wv, wo, wvo_t);
    k_transp<<<dim3(32, 8), 256, 0, stream>>>(w1, w1t, 256, 1024);
    k_transp<<<dim3(8, 32), 256, 0, stream>>>(w2, w2t, 1024, 256);

    // main pipeline
    k_attn<<<BT / 4, 256, 0, stream>>>(x, qkbT, qb, bufA);
    k_mg<2048, 256, false, true, false><<<dim3(BT / 32, 1), 256, 0, stream>>>(
        bufA, wvo_t, bvo, ln1_g, ln1_b, hb);
    k_mg<256, 1024, true, false, false><<<dim3(BT / 32, 4), 256, 0, stream>>>(
        hb, w1t, b1, nullptr, nullptr, bufA);
    k_mg<1024, 256, false, false, true><<<dim3(BT / 32, 1), 256, 0, stream>>>(
        bufA, w2t, b2, nullptr, nullptr, buf1);
    k_wsel<<<BT / 16, 256, 0, stream>>>(buf1, ln2_g, ln2_b, ww, bw, x, w_out, vs_out);
}

// Round 4
// 725.916 us; speedup vs baseline: 1.0232x; 1.0232x over previous
//
#include <hip/hip_runtime.h>
#include <hip/hip_bf16.h>
#include <math.h>

#define BT   16384
#define HIDS 256
#define NHS  8
#define NVS  20

typedef __attribute__((ext_vector_type(8))) short short8;
typedef __attribute__((ext_vector_type(4))) float floatx4;

__device__ __forceinline__ float bf2f(unsigned int u) {
    union { unsigned int u; float f; } cv; cv.u = u << 16; return cv.f;
}
__device__ __forceinline__ unsigned short f2bf(float f) {
    union { __hip_bfloat16 h; unsigned short u; } cv; cv.h = __float2bfloat16(f); return cv.u;
}
__device__ __forceinline__ unsigned int pk2(float a, float b) {
    return (unsigned int)f2bf(a) | ((unsigned int)f2bf(b) << 16);
}
__device__ __forceinline__ void gload16(const void* g, void* l) {
    __builtin_amdgcn_global_load_lds(
        (const __attribute__((address_space(1))) unsigned int*)g,
        (__attribute__((address_space(3))) unsigned int*)l, 16, 0, 0);
}

// ---------- prep: fold query into key proj -> qkbT [16][256] bf16, qb[8] ----------
__global__ __launch_bounds__(256) void k_fold(
        const float* __restrict__ cls, const float* __restrict__ wq,
        const float* __restrict__ bq, const float* __restrict__ wk,
        const float* __restrict__ bk, unsigned short* __restrict__ qkbT,
        float* __restrict__ qb) {
    __shared__ float s_q[HIDS];
    int tid = threadIdx.x;
    float acc = bq[tid];
    for (int c = 0; c < HIDS; ++c) acc += cls[c] * wq[c * HIDS + tid];
    s_q[tid] = acc;
    __syncthreads();
    int c = tid;
    #pragma unroll
    for (int h = 0; h < NHS; ++h) {
        float a = 0.f;
        #pragma unroll
        for (int d = 0; d < 32; ++d) a += wk[c * HIDS + h * 32 + d] * s_q[h * 32 + d];
        qkbT[h * HIDS + c] = f2bf(a);
    }
    #pragma unroll
    for (int h = NHS; h < 16; ++h) qkbT[h * HIDS + c] = 0;
    if (tid < NHS) {
        float a = 0.f;
        #pragma unroll
        for (int d = 0; d < 32; ++d) a += bk[tid * 32 + d] * s_q[tid * 32 + d];
        qb[tid] = a;
    }
}

// ---------- prep: bvo = bv@wo + bo ----------
__global__ __launch_bounds__(256) void k_bvo(
        const float* __restrict__ bv, const float* __restrict__ wo,
        const float* __restrict__ bo, float* __restrict__ bvo) {
    int j = threadIdx.x;
    float a = bo[j];
    for (int i = 0; i < HIDS; ++i) a += bv[i] * wo[i * HIDS + j];
    bvo[j] = a;
}

// ---------- prep: wvo_t[j][h*256+c] = sum_d wv[c][h*32+d]*wo[h*32+d][j] (bf16) ----
__global__ __launch_bounds__(256) void k_wvo(
        const float* __restrict__ wv, const float* __restrict__ wo,
        unsigned short* __restrict__ wvo_t) {
    int h = blockIdx.x >> 2;
    int j0 = (blockIdx.x & 3) * 64;
    int tid = threadIdx.x;  // c
    __shared__ float s_wo[32][64];
    #pragma unroll
    for (int i = 0; i < 8; ++i) {
        int idx = i * 256 + tid;
        int d = idx >> 6, jj = idx & 63;
        s_wo[d][jj] = wo[(h * 32 + d) * HIDS + j0 + jj];
    }
    float av[32];
    #pragma unroll
    for (int d4 = 0; d4 < 8; ++d4) {
        float4 f = *(const float4*)(wv + (size_t)tid * HIDS + h * 32 + d4 * 4);
        av[d4 * 4] = f.x; av[d4 * 4 + 1] = f.y;
        av[d4 * 4 + 2] = f.z; av[d4 * 4 + 3] = f.w;
    }
    __syncthreads();
    #pragma unroll 4
    for (int jj = 0; jj < 64; ++jj) {
        float a = 0.f;
        #pragma unroll
        for (int d = 0; d < 32; ++d) a += av[d] * s_wo[d][jj];
        wvo_t[(size_t)(j0 + jj) * 2048 + h * 256 + tid] = f2bf(a);
    }
}

// ---------- prep: transpose f32 [R][C] -> bf16 [C][R] ----------
__global__ __launch_bounds__(256) void k_transp(const float* __restrict__ in,
        unsigned short* __restrict__ out, int R, int C) {
    __shared__ float s[32][36];
    int tid = threadIdx.x;
    int ct = blockIdx.x * 32, rt = blockIdx.y * 32;
    int r = tid >> 3, c4 = (tid & 7) * 4;
    float4 f = *(const float4*)&in[(size_t)(rt + r) * C + ct + c4];
    s[r][c4] = f.x; s[r][c4 + 1] = f.y; s[r][c4 + 2] = f.z; s[r][c4 + 3] = f.w;
    __syncthreads();
    int ro = tid >> 3, k4 = (tid & 7) * 4;
    ushort4 o;
    o.x = f2bf(s[k4][ro]);     o.y = f2bf(s[k4 + 1][ro]);
    o.z = f2bf(s[k4 + 2][ro]); o.w = f2bf(s[k4 + 3][ro]);
    *(ushort4*)&out[(size_t)(ct + ro) * R + rt + k4] = o;
}

// ---------- attention: 4 tokens/block, MFMA scores, VALU mix -> xmix bf16 ----------
__global__ __launch_bounds__(256) void k_attn(
        const float* __restrict__ x, const unsigned short* __restrict__ qkbT,
        const float* __restrict__ qb, unsigned short* __restrict__ xmix) {
    __shared__ __align__(16) unsigned short sX[80 * 256];
    __shared__ float s_at[4][NVS][NHS];
    int tid = threadIdx.x;
    int wave = tid >> 6, lane = tid & 63;
    int m = lane & 15, g = lane >> 4;
    size_t t0 = (size_t)blockIdx.x * 4;

    short8 qf[8];
    #pragma unroll
    for (int kk = 0; kk < 8; ++kk)
        qf[kk] = *(const short8*)&qkbT[m * HIDS + kk * 32 + g * 8];

    const float* xg = x + t0 * (NVS * HIDS);
    #pragma unroll
    for (int i = 0; i < 10; ++i) {
        int s = i * 256 + tid;
        int row = s >> 5, cc = s & 31;
        float4 f0 = *(const float4*)(xg + s * 8);
        float4 f1 = *(const float4*)(xg + s * 8 + 4);
        uint4 pk;
        pk.x = pk2(f0.x, f0.y); pk.y = pk2(f0.z, f0.w);
        pk.z = pk2(f1.x, f1.y); pk.w = pk2(f1.z, f1.w);
        int c = cc ^ (row & 7);
        *(uint4*)&sX[row * 256 + c * 8] = pk;
    }
    __syncthreads();

    int rbase = wave * NVS;
    floatx4 sc0 = {0.f, 0.f, 0.f, 0.f}, sc1 = {0.f, 0.f, 0.f, 0.f};
    #pragma unroll
    for (int kk = 0; kk < 8; ++kk) {
        int r0 = rbase + m;
        int c0 = (kk * 4 + g) ^ (r0 & 7);
        short8 a0 = *(const short8*)&sX[r0 * 256 + c0 * 8];
        int r1 = rbase + 16 + m;
        int c1 = (kk * 4 + g) ^ (r1 & 7);
        short8 a1 = *(const short8*)&sX[r1 * 256 + c1 * 8];
        sc0 = __builtin_amdgcn_mfma_f32_16x16x32_bf16(a0, qf[kk], sc0, 0, 0, 0);
        sc1 = __builtin_amdgcn_mfma_f32_16x16x32_bf16(a1, qf[kk], sc1, 0, 0, 0);
    }
    if (m < NHS) {
        #pragma unroll
        for (int r = 0; r < 4; ++r) s_at[wave][g * 4 + r][m] = sc0[r];
        if (g == 0) {
            #pragma unroll
            for (int r = 0; r < 4; ++r) s_at[wave][16 + r][m] = sc1[r];
        }
    }
    __syncthreads();

    if (lane < NHS) {
        float qbh = qb[lane];
        float sv[NVS]; float mx = -1e30f;
        #pragma unroll
        for (int v = 0; v < NVS; ++v) {
            float sc = (s_at[wave][v][lane] + qbh) * 0.17677669529663687f;
            sv[v] = sc; mx = fmaxf(mx, sc);
        }
        float sum = 0.f;
        #pragma unroll
        for (int v = 0; v < NVS; ++v) { sv[v] = expf(sv[v] - mx); sum += sv[v]; }
        float inv = 1.f / sum;
        #pragma unroll
        for (int v = 0; v < NVS; ++v) s_at[wave][v][lane] = sv[v] * inv;
    }
    __syncthreads();

    floatx4 acc[NHS];
    #pragma unroll
    for (int h = 0; h < NHS; ++h) acc[h] = (floatx4){0.f, 0.f, 0.f, 0.f};
    #pragma unroll
    for (int v = 0; v < NVS; ++v) {
        int r = rbase + v;
        int cidx = (((lane >> 1) ^ (r & 7)) << 3) + ((lane & 1) << 2);
        uint2 u = *(const uint2*)&sX[r * 256 + cidx];
        float x0 = bf2f(u.x & 0xffffu), x1 = bf2f(u.x >> 16);
        float x2 = bf2f(u.y & 0xffffu), x3 = bf2f(u.y >> 16);
        float4 w0 = *(const float4*)&s_at[wave][v][0];
        float4 w1 = *(const float4*)&s_at[wave][v][4];
        float wv8[8] = {w0.x, w0.y, w0.z, w0.w, w1.x, w1.y, w1.z, w1.w};
        #pragma unroll
        for (int h = 0; h < NHS; ++h) {
            acc[h][0] += wv8[h] * x0; acc[h][1] += wv8[h] * x1;
            acc[h][2] += wv8[h] * x2; acc[h][3] += wv8[h] * x3;
        }
    }
    unsigned short* op = xmix + (t0 + wave) * 2048;
    #pragma unroll
    for (int h = 0; h < NHS; ++h) {
        uint2 o; o.x = pk2(acc[h][0], acc[h][1]); o.y = pk2(acc[h][2], acc[h][3]);
        *(uint2*)&op[h * 256 + lane * 4] = o;
    }
}

// ================= fused FF + selection kernel =================
// 32 tokens/block: GEMM1(K=2048)+LN1 -> GEMM2(+GELU, 4 chunks) -> GEMM3(acc)
// -> LN2 -> logits -> softmax -> weights.x ; h/h1 stay in LDS.
__global__ __launch_bounds__(256) void k_ff(
        const unsigned short* __restrict__ xmix,   // [BT][2048]
        const unsigned short* __restrict__ wvo_t,  // [256][2048]
        const float* __restrict__ bvo,
        const float* __restrict__ ln1g, const float* __restrict__ ln1b,
        const unsigned short* __restrict__ w1t,    // [1024][256]
        const float* __restrict__ b1,
        const unsigned short* __restrict__ w2t,    // [256][1024]
        const float* __restrict__ b2,
        const float* __restrict__ ln2g, const float* __restrict__ ln2b,
        const float* __restrict__ ww, const float* __restrict__ bw,
        const float* __restrict__ x,
        float* __restrict__ w_out, float* __restrict__ vs_out) {
    __shared__ __align__(16) char smem[76032];
    unsigned short* sB  = (unsigned short*)smem;            // 32 KB  B staging
    unsigned short* sA  = (unsigned short*)(smem + 32768);  // 4 KB   phase1 A
    unsigned short* sH  = (unsigned short*)(smem + 36864);  // 16 KB  LN1 out (bf16)
    unsigned short* sH1 = (unsigned short*)(smem + 53248);  // 16 KB  GELU chunk (bf16)
    float* sP    = (float*)(smem + 36864);                  // 32 KB  LN2 f32 (overlays sH+sH1)
    float* s_sum = (float*)(smem + 69632);                  // [4][32]
    float* s_sq  = (float*)(smem + 70144);                  // [4][32]
    float* s_ms  = (float*)(smem + 70656);                  // [32][2]
    float* s_lg  = (float*)(smem + 70912);                  // [32][20]
    float* s_w   = (float*)(smem + 73472);                  // [32][20]
    float* s_ww  = (float*)smem;                            // phase4 overlay on sB (20.6 KB)

    int tid = threadIdx.x;
    int wave = tid >> 6, lane = tid & 63;
    int m = lane & 15, g = lane >> 4;
    int wn = wave * 64;
    size_t t0 = (size_t)blockIdx.x * 32;

    floatx4 accA[2][4], acc3[2][4];
    #pragma unroll
    for (int i = 0; i < 2; ++i)
        #pragma unroll
        for (int j = 0; j < 4; ++j) {
            accA[i][j] = (floatx4){0.f, 0.f, 0.f, 0.f};
            acc3[i][j] = (floatx4){0.f, 0.f, 0.f, 0.f};
        }

    // -------- phase 1: h = xmix @ wvo_t + bvo, LN1 -> sH --------
    for (int k0 = 0; k0 < 2048; k0 += 64) {
        __syncthreads();
        {
            int s = tid, row = s >> 3, cc = s & 7, gc = cc ^ (row & 7);
            gload16(xmix + (t0 + row) * 2048 + k0 + gc * 8, (char*)sA + s * 16);
        }
        #pragma unroll
        for (int p = 0; p < 8; ++p) {
            int s = p * 256 + tid, row = s >> 3, cc = s & 7, gc = cc ^ (row & 7);
            gload16(wvo_t + (size_t)row * 2048 + k0 + gc * 8, (char*)sB + s * 16);
        }
        __syncthreads();
        #pragma unroll
        for (int kk = 0; kk < 2; ++kk) {
            short8 af[2], bf[4];
            #pragma unroll
            for (int i = 0; i < 2; ++i) {
                int row = i * 16 + m, c = (kk * 4 + g) ^ (row & 7);
                af[i] = *(const short8*)&sA[row * 64 + c * 8];
            }
            #pragma unroll
            for (int j = 0; j < 4; ++j) {
                int row = wn + j * 16 + m, c = (kk * 4 + g) ^ (row & 7);
                bf[j] = *(const short8*)&sB[row * 64 + c * 8];
            }
            #pragma unroll
            for (int i = 0; i < 2; ++i)
                #pragma unroll
                for (int j = 0; j < 4; ++j)
                    accA[i][j] = __builtin_amdgcn_mfma_f32_16x16x32_bf16(af[i], bf[j], accA[i][j], 0, 0, 0);
        }
    }
    {
        float vv[2][4][4];
        #pragma unroll
        for (int j = 0; j < 4; ++j) {
            float bj = bvo[wn + j * 16 + m];
            #pragma unroll
            for (int i = 0; i < 2; ++i)
                #pragma unroll
                for (int r = 0; r < 4; ++r) vv[i][j][r] = accA[i][j][r] + bj;
        }
        // LN1 row stats
        #pragma unroll
        for (int i = 0; i < 2; ++i)
            #pragma unroll
            for (int r = 0; r < 4; ++r) {
                float s = 0.f, q = 0.f;
                #pragma unroll
                for (int j = 0; j < 4; ++j) { float v = vv[i][j][r]; s += v; q += v * v; }
                #pragma unroll
                for (int mk = 1; mk < 16; mk <<= 1) {
                    s += __shfl_xor(s, mk, 64);
                    q += __shfl_xor(q, mk, 64);
                }
                if ((lane & 15) == 0) {
                    int row = i * 16 + g * 4 + r;
                    s_sum[wave * 32 + row] = s;
                    s_sq[wave * 32 + row] = q;
                }
            }
        __syncthreads();
        if (tid < 32) {
            float ts = 0.f, tq = 0.f;
            #pragma unroll
            for (int w = 0; w < 4; ++w) { ts += s_sum[w * 32 + tid]; tq += s_sq[w * 32 + tid]; }
            float mean = ts * (1.f / 256.f);
            float var = tq * (1.f / 256.f) - mean * mean;
            s_ms[tid * 2] = mean; s_ms[tid * 2 + 1] = rsqrtf(var + 1e-5f);
        }
        __syncthreads();
        float lg_[4], lb_[4];
        #pragma unroll
        for (int j = 0; j < 4; ++j) {
            lg_[j] = ln1g[wn + j * 16 + m];
            lb_[j] = ln1b[wn + j * 16 + m];
        }
        #pragma unroll
        for (int i = 0; i < 2; ++i)
            #pragma unroll
            for (int r = 0; r < 4; ++r) {
                int row = i * 16 + g * 4 + r;
                float mean = s_ms[row * 2], rstd = s_ms[row * 2 + 1];
                #pragma unroll
                for (int j = 0; j < 4; ++j) {
                    float v = (vv[i][j][r] - mean) * rstd * lg_[j] + lb_[j];
                    float v2 = __shfl_xor(v, 1);
                    if (!(lane & 1)) {
                        int colE = wn + j * 16 + m;  // m even
                        int chunk = colE >> 3;
                        int lc = ((chunk ^ (row & 7)) << 3) + (colE & 7);
                        *(unsigned int*)&sH[row * 256 + lc] = pk2(v, v2);
                    }
                }
            }
    }

    // -------- phases 2+3: h1 = gelu(h@w1+b1) in 4 chunks; acc3 += h1 @ w2 --------
    for (int nc = 0; nc < 4; ++nc) {
        #pragma unroll
        for (int i = 0; i < 2; ++i)
            #pragma unroll
            for (int j = 0; j < 4; ++j) accA[i][j] = (floatx4){0.f, 0.f, 0.f, 0.f};
        for (int k0 = 0; k0 < 256; k0 += 64) {
            __syncthreads();
            #pragma unroll
            for (int p = 0; p < 8; ++p) {
                int s = p * 256 + tid, row = s >> 3, cc = s & 7, gc = cc ^ (row & 7);
                gload16(w1t + (size_t)(nc * 256 + row) * 256 + k0 + gc * 8, (char*)sB + s * 16);
            }
            __syncthreads();
            #pragma unroll
            for (int kk = 0; kk < 2; ++kk) {
                short8 af[2], bf[4];
                #pragma unroll
                for (int i = 0; i < 2; ++i) {
                    int row = i * 16 + m;
                    int c = (k0 >> 3) + ((kk * 4 + g) ^ (row & 7));
                    af[i] = *(const short8*)&sH[row * 256 + c * 8];
                }
                #pragma unroll
                for (int j = 0; j < 4; ++j) {
                    int row = wn + j * 16 + m, c = (kk * 4 + g) ^ (row & 7);
                    bf[j] = *(const short8*)&sB[row * 64 + c * 8];
                }
                #pragma unroll
                for (int i = 0; i < 2; ++i)
                    #pragma unroll
                    for (int j = 0; j < 4; ++j)
                        accA[i][j] = __builtin_amdgcn_mfma_f32_16x16x32_bf16(af[i], bf[j], accA[i][j], 0, 0, 0);
            }
        }
        __syncthreads();  // all waves done reading sH1 from previous chunk's GEMM3
        #pragma unroll
        for (int i = 0; i < 2; ++i)
            #pragma unroll
            for (int r = 0; r < 4; ++r) {
                int row = i * 16 + g * 4 + r;
                #pragma unroll
                for (int j = 0; j < 4; ++j) {
                    float v = accA[i][j][r] + b1[nc * 256 + wn + j * 16 + m];
                    v = 0.5f * v * (1.f + erff(v * 0.70710678118654752f));
                    float v2 = __shfl_xor(v, 1);
                    if (!(lane & 1)) {
                        int colE = wn + j * 16 + m;
                        int chunk = colE >> 3;
                        int lc = ((chunk ^ (row & 7)) << 3) + (colE & 7);
                        *(unsigned int*)&sH1[row * 256 + lc] = pk2(v, v2);
                    }
                }
            }
        for (int k0 = 0; k0 < 256; k0 += 64) {
            __syncthreads();
            #pragma unroll
            for (int p = 0; p < 8; ++p) {
                int s = p * 256 + tid, row = s >> 3, cc = s & 7, gc = cc ^ (row & 7);
                gload16(w2t + (size_t)row * 1024 + nc * 256 + k0 + gc * 8, (char*)sB + s * 16);
            }
            __syncthreads();
            #pragma unroll
            for (int kk = 0; kk < 2; ++kk) {
                short8 af[2], bf[4];
                #pragma unroll
                for (int i = 0; i < 2; ++i) {
                    int row = i * 16 + m;
                    int c = (k0 >> 3) + ((kk * 4 + g) ^ (row & 7));
                    af[i] = *(const short8*)&sH1[row * 256 + c * 8];
                }
                #pragma unroll
                for (int j = 0; j < 4; ++j) {
                    int row = wn + j * 16 + m, c = (kk * 4 + g) ^ (row & 7);
                    bf[j] = *(const short8*)&sB[row * 64 + c * 8];
                }
                #pragma unroll
                for (int i = 0; i < 2; ++i)
                    #pragma unroll
                    for (int j = 0; j < 4; ++j)
                        acc3[i][j] = __builtin_amdgcn_mfma_f32_16x16x32_bf16(af[i], bf[j], acc3[i][j], 0, 0, 0);
            }
        }
    }

    // -------- LN2 -> sP (f32, rotated layout) --------
    {
        float vv[2][4][4];
        #pragma unroll
        for (int j = 0; j < 4; ++j) {
            float bj = b2[wn + j * 16 + m];
            #pragma unroll
            for (int i = 0; i < 2; ++i)
                #pragma unroll
                for (int r = 0; r < 4; ++r) vv[i][j][r] = acc3[i][j][r] + bj;
        }
        __syncthreads();  // done with sH/sH1/sB reads; s_sum reuse
        #pragma unroll
        for (int i = 0; i < 2; ++i)
            #pragma unroll
            for (int r = 0; r < 4; ++r) {
                float s = 0.f, q = 0.f;
                #pragma unroll
                for (int j = 0; j < 4; ++j) { float v = vv[i][j][r]; s += v; q += v * v; }
                #pragma unroll
                for (int mk = 1; mk < 16; mk <<= 1) {
                    s += __shfl_xor(s, mk, 64);
                    q += __shfl_xor(q, mk, 64);
                }
                if ((lane & 15) == 0) {
                    int row = i * 16 + g * 4 + r;
                    s_sum[wave * 32 + row] = s;
                    s_sq[wave * 32 + row] = q;
                }
            }
        __syncthreads();
        if (tid < 32) {
            float ts = 0.f, tq = 0.f;
            #pragma unroll
            for (int w = 0; w < 4; ++w) { ts += s_sum[w * 32 + tid]; tq += s_sq[w * 32 + tid]; }
            float mean = ts * (1.f / 256.f);
            float var = tq * (1.f / 256.f) - mean * mean;
            s_ms[tid * 2] = mean; s_ms[tid * 2 + 1] = rsqrtf(var + 1e-5f);
        }
        __syncthreads();
        #pragma unroll
        for (int i = 0; i < 2; ++i)
            #pragma unroll
            for (int r = 0; r < 4; ++r) {
                int row = i * 16 + g * 4 + r;
                float mean = s_ms[row * 2], rstd = s_ms[row * 2 + 1];
                #pragma unroll
                for (int j = 0; j < 4; ++j) {
                    int col = wn + j * 16 + m;
                    float v = (vv[i][j][r] - mean) * rstd * ln2g[col] + ln2b[col];
                    sP[row * 256 + ((col + 2 * row) & 255)] = v;
                }
            }
    }
    __syncthreads();

    // -------- stage ww+bw into LDS (overlay sB) --------
    #pragma unroll
    for (int p = 0; p < 20; ++p) {
        int idx = p * 256 + tid;
        if (idx < 5120) s_ww[idx] = ww[idx];
    }
    if (tid < 20) s_ww[5120 + tid] = bw[tid];
    __syncthreads();

    // -------- logits: 8 threads/row, u in {q, q+8, q+16} --------
    {
        int row = tid >> 3, q = tid & 7;
        float a0 = 0.f, a1 = 0.f, a2 = 0.f;
        #pragma unroll 4
        for (int c = 0; c < 256; ++c) {
            float p = sP[row * 256 + ((c + 2 * row) & 255)];
            a0 += p * s_ww[c * 20 + q];
            a1 += p * s_ww[c * 20 + q + 8];
            if (q < 4) a2 += p * s_ww[c * 20 + q + 16];
        }
        s_lg[row * 20 + q] = a0 + s_ww[5120 + q];
        s_lg[row * 20 + q + 8] = a1 + s_ww[5120 + q + 8];
        if (q < 4) s_lg[row * 20 + q + 16] = a2 + s_ww[5120 + q + 16];
    }
    __syncthreads();

    // -------- softmax per row + write w_out --------
    if (tid < 32) {
        float mx = -1e30f;
        #pragma unroll
        for (int v = 0; v < NVS; ++v) mx = fmaxf(mx, s_lg[tid * 20 + v]);
        float e[NVS]; float ssum = 0.f;
        #pragma unroll
        for (int v = 0; v < NVS; ++v) { e[v] = expf(s_lg[tid * 20 + v] - mx); ssum += e[v]; }
        float inv = 1.f / ssum;
        #pragma unroll
        for (int v = 0; v < NVS; ++v) {
            float wv_ = e[v] * inv;
            s_w[tid * 20 + v] = wv_;
            w_out[(t0 + tid) * NVS + v] = wv_;
        }
    }
    __syncthreads();

    // -------- vs_out = weights . x (8 tokens per wave) --------
    #pragma unroll
    for (int tt = 0; tt < 8; ++tt) {
        int row = wave * 8 + tt;
        const float4* xt = (const float4*)(x + (t0 + row) * (size_t)(NVS * HIDS));
        float4 acc = make_float4(0.f, 0.f, 0.f, 0.f);
        #pragma unroll
        for (int v = 0; v < NVS; ++v) {
            float w = s_w[row * 20 + v];
            float4 a = xt[v * 64 + lane];
            acc.x += w * a.x; acc.y += w * a.y; acc.z += w * a.z; acc.w += w * a.w;
        }
        ((float4*)(vs_out + (t0 + row) * HIDS))[lane] = acc;
    }
}

extern "C" void kernel_launch(void* const* d_in, const int* in_sizes, int n_in,
                              void* d_out, int out_size, void* d_ws, size_t ws_size,
                              hipStream_t stream) {
    const float* x     = (const float*)d_in[0];
    const float* cls   = (const float*)d_in[1];
    const float* wq    = (const float*)d_in[2];
    const float* bq    = (const float*)d_in[3];
    const float* wk    = (const float*)d_in[4];
    const float* bk    = (const float*)d_in[5];
    const float* wv    = (const float*)d_in[6];
    const float* bv    = (const float*)d_in[7];
    const float* wo    = (const float*)d_in[8];
    const float* bo    = (const float*)d_in[9];
    const float* ln1_g = (const float*)d_in[10];
    const float* ln1_b = (const float*)d_in[11];
    const float* w1    = (const float*)d_in[12];
    const float* b1    = (const float*)d_in[13];
    const float* w2    = (const float*)d_in[14];
    const float* b2    = (const float*)d_in[15];
    const float* ln2_g = (const float*)d_in[16];
    const float* ln2_b = (const float*)d_in[17];
    const float* ww    = (const float*)d_in[18];
    const float* bw    = (const float*)d_in[19];

    float* outf   = (float*)d_out;
    float* vs_out = outf;
    float* w_out  = outf + (size_t)BT * HIDS;

    char* ws = (char*)d_ws;
    unsigned short* qkbT = (unsigned short*)ws;                          // 8 KB
    float* qb   = (float*)(ws + 8192);
    float* bvo  = (float*)(ws + 8448);
    unsigned short* w1t   = (unsigned short*)(ws + 16384);               // 512 KB
    unsigned short* w2t   = (unsigned short*)(ws + 16384 + 524288);      // 512 KB
    unsigned short* wvo_t = (unsigned short*)(ws + 16384 + 1048576);     // 1 MB
    unsigned short* bufA  = (unsigned short*)(ws + 16384 + 2097152);     // 67.1 MB xmix

    // prep
    k_fold<<<1, 256, 0, stream>>>(cls, wq, bq, wk, bk, qkbT, qb);
    k_bvo<<<1, 256, 0, stream>>>(bv, wo, bo, bvo);
    k_wvo<<<32, 256, 0, stream>>>(wv, wo, wvo_t);
    k_transp<<<dim3(32, 8), 256, 0, stream>>>(w1, w1t, 256, 1024);
    k_transp<<<dim3(8, 32), 256, 0, stream>>>(w2, w2t, 1024, 256);

    // main pipeline
    k_attn<<<BT / 4, 256, 0, stream>>>(x, qkbT, qb, bufA);
    k_ff<<<BT / 32, 256, 0, stream>>>(bufA, wvo_t, bvo, ln1_g, ln1_b,
                                      w1t, b1, w2t, b2, ln2_g, ln2_b,
                                      ww, bw, x, w_out, vs_out);
}